// Round 7
// baseline (784.103 us; speedup 1.0000x reference)
//
#include <hip/hip_runtime.h>
#include <hip/hip_bf16.h>
#include <stdint.h>

// GRU sequence decoder, fused. B=32768, H=L=512, VOCAB=10, SEQ=6.
// R7: occupancy via register diet. R6 evidence: zero spill (WRITE=intentional),
// VGPR=108 reported, yet occupancy pinned at 23.6% (1 block/CU) -> effective
// footprint ~= arch + 48 AGPR acc > 128 -> 3 waves/SIMD -> second block can't
// co-reside. Fix: split each pass into two half-passes so acc peak halves:
//   A: gh_r, gh_z (acc 32) -> rv,zv = sigm(gi+gh) kept in f32 regs (32)
//   B: gh_n (acc 16) -> nv -> h_new -> hst
// Weight chunks still read ONCE per block-step (r,z in A; n in B). LDS h-frag
// reads double (hidden). Same split in the gi phase. Everything else = R6:
//  - 8 waves, wave owns 4 jtiles x all 4 btiles; A=weight frag, B=h frag.
//  - gi in ws per-lane fragment order (same-lane RAW, coalesced).
//  - h only in LDS (XOR swizzle); h_new streamed via hst (global, L2) to
//    avoid the 32-reg hold across the barrier.
//  - __launch_bounds__(512,2) = min 2 BLOCKS/CU (hipcc CUDA semantics, R3/R4).

typedef __bf16 bf16_t;
typedef bf16_t bf16x8 __attribute__((ext_vector_type(8)));
typedef bf16_t bf16x4 __attribute__((ext_vector_type(4)));
typedef float  f32x4  __attribute__((ext_vector_type(4)));
typedef float  f32x2  __attribute__((ext_vector_type(2)));

#define THREADS 512
#define BM      64
#define NBLK    512
#define NSTEP   6

// ws layout (bytes)
#define WIH_OFF 0u            // 96 nt * 16 kk * 64 lane * 16B = 1572864
#define WHH_OFF 1572864u
#define WOP_OFF 3145728u      // 16 kk * 64 lane * 16B = 16384
#define GI_OFF  4194304u      // 512 blk * 24576 chunks * 8B = 100663296
#define HST_OFF 104857600u    // 512 blk * 128 chunks * 512B = 33554432

static __device__ __forceinline__ float sigm(float v) { return 1.0f / (1.0f + __expf(-v)); }
static __device__ __forceinline__ float tanhf_(float v) {
  v = fminf(fmaxf(v, -12.0f), 12.0f);
  float e = __expf(2.0f * v);
  return 1.0f - 2.0f / (e + 1.0f);
}
static __device__ __forceinline__ f32x4 up4(bf16x4 v) {
  f32x4 o; o[0] = (float)v[0]; o[1] = (float)v[1]; o[2] = (float)v[2]; o[3] = (float)v[3];
  return o;
}
static __device__ __forceinline__ bf16x4 pk4(f32x4 v) {
  bf16x4 o; o[0] = (bf16_t)v[0]; o[1] = (bf16_t)v[1]; o[2] = (bf16_t)v[2]; o[3] = (bf16_t)v[3];
  return o;
}

// Pack weights into MFMA A-frag order:
//   chunk[(nt*16 + kk)*64 + lane] = w[nt*16 + (lane&15)][kk*32 + (lane>>4)*8 .. +8]
__global__ void prep_kernel(const float* __restrict__ wih_f, const float* __restrict__ whh_f,
                            const float* __restrict__ wout_f,
                            bf16x8* __restrict__ wihPk, bf16x8* __restrict__ whhPk,
                            bf16x8* __restrict__ wopPk) {
  int c = blockIdx.x * 256 + threadIdx.x;
  int lane = c & 63, l15 = lane & 15, lk = (lane >> 4) & 3;
  if (c < 196608) {
    int cid = (c < 98304) ? c : c - 98304;
    const float* src = (c < 98304) ? wih_f : whh_f;
    bf16x8* dst = (c < 98304) ? wihPk : whhPk;
    int kk = (cid >> 6) & 15;
    int nt = cid >> 10;
    const float* p = src + (size_t)(nt * 16 + l15) * 512 + kk * 32 + lk * 8;
    bf16x8 o;
    #pragma unroll
    for (int i = 0; i < 8; ++i) o[i] = (bf16_t)p[i];
    dst[cid] = o;
  } else if (c < 197632) {
    int cid = c - 196608;          // vocab tile: 16 kk * 64 lane
    int kk = cid >> 6;
    bf16x8 o;
    if (l15 < 10) {
      const float* p = wout_f + (size_t)l15 * 512 + kk * 32 + lk * 8;
      #pragma unroll
      for (int i = 0; i < 8; ++i) o[i] = (bf16_t)p[i];
    } else {
      #pragma unroll
      for (int i = 0; i < 8; ++i) o[i] = (bf16_t)0.0f;
    }
    wopPk[cid] = o;
  }
}

__global__ __launch_bounds__(THREADS, 2) void gru_kernel(
    const float* __restrict__ x, const float* __restrict__ b_ih,
    const float* __restrict__ b_hh, const float* __restrict__ b_out,
    const bf16x8* __restrict__ wih, const bf16x8* __restrict__ whh,
    const bf16x8* __restrict__ wop,
    bf16x4* __restrict__ gi, bf16x4* __restrict__ hst, float* __restrict__ out) {
  // h tile: 64 rows x 512 bf16, row = 1024B; logical col-byte L of row r at
  // physical L ^ ((r&7)<<4).
  __shared__ __align__(16) char hlds[BM * 1024];

  const int tid   = (int)threadIdx.x;
  const int lane  = tid & 63;
  const int wq    = tid >> 6;      // 0..7: wave owns jtiles [wq*4, wq*4+4)
  const int l15   = lane & 15;
  const int lk    = lane >> 4;
  const int brow0 = (int)blockIdx.x * BM;
  const int swz   = (l15 & 7) << 4;
  const int kbase = (lk * 16) ^ swz;        // b128 read col base (XOR with kk*64)
  const int cbase = (lk * 8) ^ swz;         // b64 cell col base (XOR with jt*32)

  // ---------------- phase 0: x -> bf16 -> hlds (h0 = x) ----------------
  #pragma unroll
  for (int it = 0; it < 16; ++it) {
    int f4  = it * THREADS + tid;
    int row = f4 >> 7, c4 = f4 & 127;
    float4 v = ((const float4*)(x + (size_t)(brow0 + row) * 512))[c4];
    bf16x4 h4 = { (bf16_t)v.x, (bf16_t)v.y, (bf16_t)v.z, (bf16_t)v.w };
    *(bf16x4*)(&hlds[row * 1024 + ((c4 * 8) ^ ((row & 7) << 4))]) = h4;
  }
  __syncthreads();

  const size_t gibase = (size_t)blockIdx.x * 24576;  // bf16x4 chunks per block
  // gi chunk: ((jt*3 + g)*4 + bt)*64 + lane,  jt = wq*4 + p
  const size_t hstbase = (size_t)blockIdx.x * 8192;  // bf16x4: 128 chunks * 64
  // hst chunk: (jt*4 + bt)*64 + lane

  // ---------------- gi phase: gi = x @ w_ih^T + biases (split r,z | n) -----
  #pragma unroll
  for (int p = 0; p < 4; ++p) {
    const int jt = wq * 4 + p;
    const int cb = jt * 12;
    const int j  = jt * 16 + lk * 4;
    {   // half A: r, z
      f32x4 accR[4], accZ[4];
      #pragma unroll
      for (int bt = 0; bt < 4; ++bt) {
        accR[bt] = (f32x4){0.f, 0.f, 0.f, 0.f};
        accZ[bt] = (f32x4){0.f, 0.f, 0.f, 0.f};
      }
      #pragma unroll 2
      for (int kk = 0; kk < 16; ++kk) {
        bf16x8 hf[4];
        #pragma unroll
        for (int bt = 0; bt < 4; ++bt)
          hf[bt] = *(const bf16x8*)(&hlds[(bt * 16 + l15) * 1024 + ((kk * 64) ^ kbase)]);
        bf16x8 wfR = wih[((0 * 32 + jt) * 16 + kk) * 64 + lane];
        bf16x8 wfZ = wih[((1 * 32 + jt) * 16 + kk) * 64 + lane];
        #pragma unroll
        for (int bt = 0; bt < 4; ++bt) {
          accR[bt] = __builtin_amdgcn_mfma_f32_16x16x32_bf16(wfR, hf[bt], accR[bt], 0, 0, 0);
          accZ[bt] = __builtin_amdgcn_mfma_f32_16x16x32_bf16(wfZ, hf[bt], accZ[bt], 0, 0, 0);
        }
      }
      f32x4 b0 = *(const f32x4*)(b_ih + j) + *(const f32x4*)(b_hh + j);
      f32x4 b1 = *(const f32x4*)(b_ih + 512 + j) + *(const f32x4*)(b_hh + 512 + j);
      #pragma unroll
      for (int bt = 0; bt < 4; ++bt) {
        gi[gibase + ((size_t)(cb + 0 + bt) << 6) + lane] = pk4(accR[bt] + b0);
        gi[gibase + ((size_t)(cb + 4 + bt) << 6) + lane] = pk4(accZ[bt] + b1);
      }
    }
    {   // half B: n
      f32x4 accN[4];
      #pragma unroll
      for (int bt = 0; bt < 4; ++bt) accN[bt] = (f32x4){0.f, 0.f, 0.f, 0.f};
      #pragma unroll 2
      for (int kk = 0; kk < 16; ++kk) {
        bf16x8 hf[4];
        #pragma unroll
        for (int bt = 0; bt < 4; ++bt)
          hf[bt] = *(const bf16x8*)(&hlds[(bt * 16 + l15) * 1024 + ((kk * 64) ^ kbase)]);
        bf16x8 wfN = wih[((2 * 32 + jt) * 16 + kk) * 64 + lane];
        #pragma unroll
        for (int bt = 0; bt < 4; ++bt)
          accN[bt] = __builtin_amdgcn_mfma_f32_16x16x32_bf16(wfN, hf[bt], accN[bt], 0, 0, 0);
      }
      f32x4 b2 = *(const f32x4*)(b_ih + 1024 + j);   // b_hh_n stays separate (x r)
      #pragma unroll
      for (int bt = 0; bt < 4; ++bt)
        gi[gibase + ((size_t)(cb + 8 + bt) << 6) + lane] = pk4(accN[bt] + b2);
    }
  }
  // (no barrier: hlds unchanged; gi is same-lane RAW, HW-ordered)

  // ---------------- 6 recurrent steps ----------------
  for (int t = 0; t < NSTEP; ++t) {
    #pragma unroll
    for (int p = 0; p < 4; ++p) {
      const int jt = wq * 4 + p;
      const int cb = jt * 12;

      // ---- half A: gh_r, gh_z -> rv, zv (f32 regs) ----
      f32x4 rv[4], zv[4];
      {
        f32x4 accR[4], accZ[4];
        #pragma unroll
        for (int bt = 0; bt < 4; ++bt) {
          accR[bt] = (f32x4){0.f, 0.f, 0.f, 0.f};
          accZ[bt] = (f32x4){0.f, 0.f, 0.f, 0.f};
        }
        #pragma unroll 2
        for (int kk = 0; kk < 16; ++kk) {
          bf16x8 hf[4];
          #pragma unroll
          for (int bt = 0; bt < 4; ++bt)
            hf[bt] = *(const bf16x8*)(&hlds[(bt * 16 + l15) * 1024 + ((kk * 64) ^ kbase)]);
          bf16x8 wfR = whh[((0 * 32 + jt) * 16 + kk) * 64 + lane];
          bf16x8 wfZ = whh[((1 * 32 + jt) * 16 + kk) * 64 + lane];
          #pragma unroll
          for (int bt = 0; bt < 4; ++bt) {
            accR[bt] = __builtin_amdgcn_mfma_f32_16x16x32_bf16(wfR, hf[bt], accR[bt], 0, 0, 0);
            accZ[bt] = __builtin_amdgcn_mfma_f32_16x16x32_bf16(wfZ, hf[bt], accZ[bt], 0, 0, 0);
          }
        }
        #pragma unroll
        for (int bt = 0; bt < 4; ++bt) {
          f32x4 gr = up4(gi[gibase + ((size_t)(cb + 0 + bt) << 6) + lane]);
          f32x4 gz = up4(gi[gibase + ((size_t)(cb + 4 + bt) << 6) + lane]);
          #pragma unroll
          for (int r = 0; r < 4; ++r) {
            rv[bt][r] = sigm(gr[r] + accR[bt][r]);
            zv[bt][r] = sigm(gz[r] + accZ[bt][r]);
          }
        }
      }

      // ---- half B: gh_n -> h_new -> hst ----
      {
        f32x4 accN[4];
        #pragma unroll
        for (int bt = 0; bt < 4; ++bt) accN[bt] = (f32x4){0.f, 0.f, 0.f, 0.f};
        #pragma unroll 2
        for (int kk = 0; kk < 16; ++kk) {
          bf16x8 hf[4];
          #pragma unroll
          for (int bt = 0; bt < 4; ++bt)
            hf[bt] = *(const bf16x8*)(&hlds[(bt * 16 + l15) * 1024 + ((kk * 64) ^ kbase)]);
          bf16x8 wfN = whh[((2 * 32 + jt) * 16 + kk) * 64 + lane];
          #pragma unroll
          for (int bt = 0; bt < 4; ++bt)
            accN[bt] = __builtin_amdgcn_mfma_f32_16x16x32_bf16(wfN, hf[bt], accN[bt], 0, 0, 0);
        }
        int j = jt * 16 + lk * 4;
        f32x4 bn4 = *(const f32x4*)(b_hh + 1024 + j);
        #pragma unroll
        for (int bt = 0; bt < 4; ++bt) {
          f32x4 gn  = up4(gi[gibase + ((size_t)(cb + 8 + bt) << 6) + lane]);
          f32x4 hov = up4(*(const bf16x4*)(&hlds[(bt * 16 + l15) * 1024 +
                                                 ((jt * 32) ^ cbase)]));
          f32x4 hv;
          #pragma unroll
          for (int r = 0; r < 4; ++r) {
            float nv = tanhf_(gn[r] + rv[bt][r] * (accN[bt][r] + bn4[r]));
            hv[r] = (1.0f - zv[bt][r]) * nv + zv[bt][r] * hov[r];
          }
          hst[hstbase + ((size_t)((jt << 2) + bt) << 6) + lane] = pk4(hv);
        }
      }
    }
    __syncthreads();   // all waves done reading h_t; hst stores drained (vmcnt)

    // copy-back: reload own chunks from hst (L2-hit, coalesced), ds_write hlds
    #pragma unroll
    for (int p = 0; p < 4; ++p) {
      const int jt = wq * 4 + p;
      #pragma unroll
      for (int bt = 0; bt < 4; ++bt) {
        bf16x4 v = hst[hstbase + ((size_t)((jt << 2) + bt) << 6) + lane];
        *(bf16x4*)(&hlds[(bt * 16 + l15) * 1024 + ((jt * 32) ^ cbase)]) = v;
      }
    }
    __syncthreads();   // h_{t+1} visible

    // logits_t = h_{t+1} @ w_out^T + b_out ; waves 0..3 each own one btile
    if (wq < 4) {
      f32x4 lacc = (f32x4){0.f, 0.f, 0.f, 0.f};
      #pragma unroll 2
      for (int kk = 0; kk < 16; ++kk) {
        bf16x8 hf = *(const bf16x8*)(&hlds[(wq * 16 + l15) * 1024 + ((kk * 64) ^ kbase)]);
        bf16x8 wf = wop[kk * 64 + lane];
        lacc = __builtin_amdgcn_mfma_f32_16x16x32_bf16(wf, hf, lacc, 0, 0, 0);
      }
      size_t ob = (size_t)(brow0 + wq * 16 + l15) * 60 + t * 10 + lk * 4;
      if (lk < 2) {
        f32x2 a = { lacc[0] + b_out[lk * 4 + 0], lacc[1] + b_out[lk * 4 + 1] };
        f32x2 b = { lacc[2] + b_out[lk * 4 + 2], lacc[3] + b_out[lk * 4 + 3] };
        *(f32x2*)(out + ob) = a;
        *(f32x2*)(out + ob + 2) = b;
      } else if (lk == 2) {
        f32x2 a = { lacc[0] + b_out[8], lacc[1] + b_out[9] };
        *(f32x2*)(out + ob) = a;
      }
    }
  }
}

extern "C" void kernel_launch(void* const* d_in, const int* in_sizes, int n_in,
                              void* d_out, int out_size, void* d_ws, size_t ws_size,
                              hipStream_t stream) {
  const float* x     = (const float*)d_in[0];
  const float* wih_f = (const float*)d_in[1];
  const float* whh_f = (const float*)d_in[2];
  const float* b_ih  = (const float*)d_in[3];
  const float* b_hh  = (const float*)d_in[4];
  const float* wout  = (const float*)d_in[5];
  const float* b_out = (const float*)d_in[6];

  char* ws = (char*)d_ws;
  bf16x8* wihPk = (bf16x8*)(ws + WIH_OFF);
  bf16x8* whhPk = (bf16x8*)(ws + WHH_OFF);
  bf16x8* wopPk = (bf16x8*)(ws + WOP_OFF);
  bf16x4* gi    = (bf16x4*)(ws + GI_OFF);
  bf16x4* hst   = (bf16x4*)(ws + HST_OFF);

  prep_kernel<<<772, 256, 0, stream>>>(wih_f, whh_f, wout, wihPk, whhPk, wopPk);
  gru_kernel<<<NBLK, THREADS, 0, stream>>>(x, b_ih, b_hh, b_out,
                                           wihPk, whhPk, wopPk, gi, hst, (float*)d_out);
}